// Round 1
// 554.981 us; speedup vs baseline: 1.0414x; 1.0414x over previous
//
#include <hip/hip_runtime.h>
#include <hip/hip_bf16.h>

// Problem constants: B=8, XL=128, QL=16, VL=256, D=256 -> 1024 (b,x) pairs.
#define NPAIR 1024
#define DD    256
#define QL    16
#define VL    256
#define KSTR  264   // padded LDS row stride in bf16 elems (528B, 8B aligned)

// ws layout (bytes):
//   [0]       flag (int)          mask dtype: 1=byte, 0=int32
//   [4]       s0 (float)
//   [1024)    mb[256] f32         at 1024
//   [2048)    u[256] f32          at 2048
//   [4096)    MT[256][256] bf16   at 4096  (131072 bytes, ends 135168)
//   [135168)  vwT[64][256][4] f32 (256 KB) transposed vw_w for coalesced matvec
#define WS_MB   1024
#define WS_U    2048
#define WS_MT   4096
#define WS_VWT  135168

typedef __bf16 bf16x8 __attribute__((ext_vector_type(8)));
typedef __bf16 bf16x4 __attribute__((ext_vector_type(4)));
typedef float  f32x4  __attribute__((ext_vector_type(4)));

// ---------------- weight-fold precompute (+ mask dtype detect + vwT) ----------------
__global__ __launch_bounds__(256) void sa_precompute(const float* __restrict__ qw,
                                                     const float* __restrict__ qb,
                                                     const float* __restrict__ kw,
                                                     const float* __restrict__ kb,
                                                     const float* __restrict__ vww,
                                                     const unsigned int* __restrict__ maskw,
                                                     char* __restrict__ ws) {
    int c = blockIdx.x, e = threadIdx.x;
    float acc = 0.f;
    #pragma unroll 16
    for (int d = 0; d < 256; ++d) acc += qw[d*256 + e] * kw[d*256 + c];   // MT[c][e]
    ((__bf16*)(ws + WS_MT))[c*256 + e] = (__bf16)acc;

    // vwT[c>>2][d=e][c&3] = vw_w[e][c]  -> coalesced float4 reads in phase 5
    ((float*)(ws + WS_VWT))[(c >> 2)*1024 + e*4 + (c & 3)] = vww[e*256 + c];

    if (c == 0) {                          // mb[e] = sum_d qb[d]*kw[d][e]
        float a2 = 0.f;
        #pragma unroll 16
        for (int d = 0; d < 256; ++d) a2 += qb[d] * kw[d*256 + e];
        ((float*)(ws + WS_MB))[e] = a2;
    } else if (c == 1) {                   // u[e] = sum_d qw[d][e]*kb[d]
        float a2 = 0.f;
        #pragma unroll 16
        for (int d = 0; d < 256; ++d) a2 += qw[d*256 + e] * kb[d];
        ((float*)(ws + WS_U))[e] = a2;
    } else if (c == 2 && e == 0) {         // s0 = qb . kb
        float a2 = 0.f;
        #pragma unroll 16
        for (int d = 0; d < 256; ++d) a2 += qb[d] * kb[d];
        ((float*)(ws + 4))[0] = a2;
    } else if (c == 3) {
        // byte-packed bools read as u32 give values outside {0,1} w.p. ~1
        __shared__ int f;
        if (e == 0) f = 0;
        __syncthreads();
        if (maskw[e] & ~1u) atomicOr(&f, 1);
        __syncthreads();
        if (e == 0) *(int*)ws = f;
    }
}

__device__ __forceinline__ float blockReduceSum(float v, float* red, int tid) {
    __syncthreads();
    #pragma unroll
    for (int off = 32; off >= 1; off >>= 1) v += __shfl_xor(v, off);
    if ((tid & 63) == 0) red[tid >> 6] = v;
    __syncthreads();
    return (red[0] + red[1]) + (red[2] + red[3]);
}

// ---------------- Fused main kernel: one block per (b,x) pair ----------------
// proj (MFMA) -> K stream (256 rows) -> in-LDS softmax -> V stream -> out matvec.
__global__ __launch_bounds__(256) void sa_fused(const float* __restrict__ qg,
                                                const float* __restrict__ kg,
                                                const float* __restrict__ vg,
                                                const void*  __restrict__ maskp,
                                                const float* __restrict__ vwb,
                                                const char*  __restrict__ ws,
                                                float* __restrict__ outp) {
    const int p    = blockIdx.x;
    const int tid  = threadIdx.x;
    const int lane = tid & 63;
    const int w    = tid >> 6;
    const int col  = lane & 15;
    const int quad = lane >> 4;

    const int    flag = *(const int*)ws;
    const float  s0   = *(const float*)(ws + 4);
    const float* mb   = (const float*)(ws + WS_MB);
    const float* u    = (const float*)(ws + WS_U);
    const __bf16* MT  = (const __bf16*)(ws + WS_MT);

    const float* Q = qg + (size_t)p * (QL * DD);
    const float* K = kg + (size_t)p * (VL * DD);
    const float* V = vg + (size_t)p * (VL * DD);

    __shared__ __align__(16) __bf16 q_lds[16 * KSTR];
    __shared__ __align__(16) __bf16 qk_lds[16 * KSTR];
    __shared__ __align__(16) float part[256];
    __shared__ float sbias_lds[16];
    __shared__ __align__(16) float ta_lds[256];
    __shared__ __align__(16) float attn_lds[256];
    __shared__ __align__(16) float wpart[4][256];
    __shared__ __align__(16) float w_lds[256];
    __shared__ float red[4];

    // ---- q (fp32) -> bf16 LDS
    {
        const float4* Q4 = (const float4*)Q;
        #pragma unroll
        for (int it = 0; it < 4; ++it) {
            int idx = tid + it * 256;
            float4 v4 = Q4[idx];
            int f = idx * 4; int i = f >> 8; int e = f & 255;
            bf16x4 t; t[0] = (__bf16)v4.x; t[1] = (__bf16)v4.y;
                      t[2] = (__bf16)v4.z; t[3] = (__bf16)v4.w;
            *(bf16x4*)(&q_lds[i * KSTR + e]) = t;
        }
    }
    // ---- sbias partials (f32 Q for precision)
    {
        int i = tid >> 4, seg = tid & 15;
        float s = 0.f;
        const float* qrow = Q + i * DD + seg * 16;
        const float* useg = u + seg * 16;
        #pragma unroll
        for (int e = 0; e < 16; ++e) s += qrow[e] * useg[e];
        part[i * 16 + seg] = s;
    }
    __syncthreads();
    if (tid < 16) {
        float s = s0;
        #pragma unroll
        for (int seg = 0; seg < 16; ++seg) s += part[tid * 16 + seg];
        sbias_lds[tid] = s;
    }

    // ---- qk = q @ MT + mb (MFMA)
    {
        #pragma unroll
        for (int t = 0; t < 4; ++t) {
            int cc = (w * 4 + t) * 16 + col;
            float mbv = mb[cc];
            f32x4 acc; acc[0] = mbv; acc[1] = mbv; acc[2] = mbv; acc[3] = mbv;
            const __bf16* arow = &q_lds[col * KSTR + quad * 8];
            const __bf16* brow = &MT[(size_t)cc * 256 + quad * 8];
            #pragma unroll
            for (int k0 = 0; k0 < 256; k0 += 32) {
                bf16x8 a = *(const bf16x8*)(arow + k0);
                bf16x8 b = *(const bf16x8*)(brow + k0);
                acc = __builtin_amdgcn_mfma_f32_16x16x32_bf16(a, b, acc, 0, 0, 0);
            }
            #pragma unroll
            for (int r = 0; r < 4; ++r)
                qk_lds[(quad * 4 + r) * KSTR + cc] = (__bf16)acc[r];
        }
    }
    __syncthreads();

    // ---- K stream: 4 tiles of 64 rows. Batched loads, max over q per K row.
    {
        bf16x8 afrag[8];
        #pragma unroll
        for (int s = 0; s < 8; ++s)
            afrag[s] = *(const bf16x8*)(&qk_lds[col * KSTR + quad * 8 + s * 32]);

        #pragma unroll 1
        for (int vt = 0; vt < 4; ++vt) {
            int vrow = vt * 64 + w * 16 + col;
            const float* Krow = K + (size_t)vrow * DD + quad * 8;
            float4 b0[8], b1[8];
            #pragma unroll
            for (int s = 0; s < 8; ++s) {           // 16 loads issued up front
                b0[s] = *(const float4*)(Krow + s * 32);
                b1[s] = *(const float4*)(Krow + s * 32 + 4);
            }
            f32x4 acc;
            #pragma unroll
            for (int r = 0; r < 4; ++r) acc[r] = sbias_lds[quad * 4 + r];
            #pragma unroll
            for (int s = 0; s < 8; ++s) {
                bf16x8 b;
                b[0] = (__bf16)b0[s].x; b[1] = (__bf16)b0[s].y;
                b[2] = (__bf16)b0[s].z; b[3] = (__bf16)b0[s].w;
                b[4] = (__bf16)b1[s].x; b[5] = (__bf16)b1[s].y;
                b[6] = (__bf16)b1[s].z; b[7] = (__bf16)b1[s].w;
                acc = __builtin_amdgcn_mfma_f32_16x16x32_bf16(afrag[s], b, acc, 0, 0, 0);
            }
            float m4 = fmaxf(fmaxf(acc[0], acc[1]), fmaxf(acc[2], acc[3]));
            m4 = fmaxf(m4, __shfl_xor(m4, 16));
            m4 = fmaxf(m4, __shfl_xor(m4, 32));
            if (quad == 0) ta_lds[vrow] = m4;
        }
    }
    __syncthreads();

    // ---- softmax over ta (in LDS)
    float S;
    {
        float myv = ta_lds[tid];
        float ssq = blockReduceSum(myv * myv, red, tid);
        float rn  = 1.0f / sqrtf(ssq);
        bool masked;
        if (flag) masked = ((const unsigned char*)maskp)[(size_t)p * 256 + tid] != 0;
        else      masked = ((const int*)maskp)[(size_t)p * 256 + tid] != 0;
        float cnt = blockReduceSum(masked ? 0.f : 1.f, red, tid);
        float val = masked ? -10.f : (myv * rn);
        float ex  = expf(val);
        float se  = blockReduceSum(ex, red, tid);
        S = (cnt == 0.f) ? 0.f : 1.f;
        attn_lds[tid] = (cnt == 0.f) ? 0.f : (ex / se);
    }
    __syncthreads();

    // ---- w[c] = sum_v attn[v] * V[v][c], per-wave contiguous float4 row loads
    {
        const f32x4* V4 = (const f32x4*)V;
        f32x4 wa; wa[0] = 0.f; wa[1] = 0.f; wa[2] = 0.f; wa[3] = 0.f;
        #pragma unroll 4
        for (int j = 0; j < 64; ++j) {
            int row = (j << 2) | w;                 // 4 waves cover rows 4j..4j+3
            float a = attn_lds[row];
            f32x4 r4 = V4[row * 64 + lane];         // 1 KB contiguous per wave-inst
            wa += a * r4;
        }
        *(f32x4*)&wpart[w][lane * 4] = wa;
    }
    __syncthreads();
    w_lds[tid] = (wpart[0][tid] + wpart[1][tid]) + (wpart[2][tid] + wpart[3][tid]);
    __syncthreads();

    // ---- out[d] = vw_w[d,:] . w + vb[d]*S, coalesced via transposed vwT
    {
        const f32x4* T4 = (const f32x4*)(ws + WS_VWT);
        f32x4 acc4; acc4[0] = 0.f; acc4[1] = 0.f; acc4[2] = 0.f; acc4[3] = 0.f;
        #pragma unroll 8
        for (int cq = 0; cq < 64; ++cq) {
            f32x4 m4 = T4[cq * 256 + tid];          // lanes contiguous 16B -> coalesced
            f32x4 wv = *(const f32x4*)&w_lds[cq * 4];
            acc4 += m4 * wv;
        }
        float accO = vwb[tid] * S + (acc4[0] + acc4[1]) + (acc4[2] + acc4[3]);
        outp[(size_t)p * 256 + tid] = accO;
    }
}

extern "C" void kernel_launch(void* const* d_in, const int* in_sizes, int n_in,
                              void* d_out, int out_size, void* d_ws, size_t ws_size,
                              hipStream_t stream) {
    const float* q    = (const float*)d_in[0];
    const float* k    = (const float*)d_in[1];
    const float* v    = (const float*)d_in[2];
    const void*  mask = d_in[3];
    const float* qw_w = (const float*)d_in[4];
    const float* qw_b = (const float*)d_in[5];
    const float* kw_w = (const float*)d_in[6];
    const float* kw_b = (const float*)d_in[7];
    const float* vw_w = (const float*)d_in[8];
    const float* vw_b = (const float*)d_in[9];

    char* ws = (char*)d_ws;

    hipLaunchKernelGGL(sa_precompute, dim3(256), dim3(256), 0, stream,
                       qw_w, qw_b, kw_w, kw_b, vw_w, (const unsigned int*)mask, ws);
    hipLaunchKernelGGL(sa_fused, dim3(NPAIR), dim3(256), 0, stream,
                       q, k, v, mask, vw_b, (const char*)ws, (float*)d_out);
}